// Round 2
// baseline (116.245 us; speedup 1.0000x reference)
//
#include <hip/hip_runtime.h>

#define BB 32
#define HH 512
#define WW 512
#define HW (HH * WW)
#define NPIX_F 8388608.0f          // 32*512*512
#define R1 16                      // output rows per block
#define NSTR (HH / R1)             // 32 stripes per image
#define NB (BB * NSTR)             // 1024 blocks (one full residency round)
#define NLOAD (R1 + 30)            // 46 input rows per stripe
#define QP 4                       // quad halo padding each side
#define NQP (128 + 2 * QP)         // 136 padded quads per row
#define VROWF (NQP * 4)            // 544 floats per V row

// lgkmcnt-only barrier: LDS writes visible to the block WITHOUT draining
// vmcnt — in-flight global loads (tail rows, pred prefetch) survive it.
#define BARRIER_LDS() asm volatile("s_waitcnt lgkmcnt(0)\n\ts_barrier" ::: "memory")

__device__ __forceinline__ void elemwise4(const float h0, const float h1,
                                          const float h2, const float h3,
                                          const float4 t, const float4 p,
                                          float& a_bce, float& a_w,
                                          float& a_i, float& a_u)
{
    const float hv[4] = {h0, h1, h2, h3};
    const float tv[4] = {t.x, t.y, t.z, t.w};
    const float pv[4] = {p.x, p.y, p.z, p.w};
    const float inv961 = (1.0f / 961.0f);
    #pragma unroll
    for (int j = 0; j < 4; ++j) {
        const float ap = hv[j] * inv961;
        const float w  = fmaf(5.0f, fabsf(ap - tv[j]), 1.0f);
        const float pr = pv[j];
        const float ea = __expf(-fabsf(pr));                  // exp(-|pr|)
        const float iv = __builtin_amdgcn_rcpf(1.0f + ea);
        const float pp = (pr >= 0.0f) ? iv : (1.0f - iv);     // sigmoid
        const float sp = fmaxf(pr, 0.0f) + __logf(1.0f + ea); // softplus
        a_bce += sp - pr * tv[j];
        a_w   += w;
        a_i   += pp * tv[j] * w;
        a_u   += (pp + tv[j]) * w;
    }
}

// One block = one (image, 16-row stripe). Phase 1: vertical 31-row running
// sums into LDS (fp32). Two-chunk schedule: k=0..37 emits V rows 0..7 (all
// 46 row-loads are ISSUED by k=37 via the 8-deep ring), lgkm-barrier,
// chunk-A compute on rows 0..7 overlaps the in-flight tail loads, tail
// k=38..45 (register-only) emits rows 8..15, lgkm-barrier, chunk-B.
// Phase 2: each lane owns 2 ADJACENT quads -> 10 ds_read_b128/row (vs 18)
// and incremental F. Pred preloaded (cold); targ re-read is L1/L2-hot.
__global__ __launch_bounds__(256, 4)
void fused_kernel(const float* __restrict__ pred, const float* __restrict__ targ,
                  float4* __restrict__ part)
{
    const int t    = threadIdx.x;          // 0..255
    const int lane = t & 63;
    const int w    = t >> 6;               // wave 0..3
    // XCD-bijective swizzle: each XCD gets 128 consecutive ids = 4 images.
    const int orig = blockIdx.x;
    const int bi   = (orig & 7) * (NB / 8) + (orig >> 3);
    const int stripe = bi & (NSTR - 1);
    const int b      = bi >> 5;
    const int r0 = stripe * R1;

    __shared__ __align__(16) float Vl[R1][VROWF];   // 34816 B -> 4 blocks/CU
    __shared__ float4 comb[4];

    const float* tgb = targ + (size_t)b * HW;
    const float* prb = pred + (size_t)b * HW;

    // ---- preload pred (only cold phase-2 data); wave w owns rows w+4i ----
    float4 tP[4][2];
    #pragma unroll
    for (int i = 0; i < 4; ++i) {
        const float4* p4 = (const float4*)(prb + (size_t)(r0 + w + 4 * i) * WW);
        tP[i][0] = p4[2 * lane];
        tP[i][1] = p4[2 * lane + 1];
    }

    // ---- zero the horizontal halo quads (4 each side x 16 rows) ----
    if (t < 128) {
        const int r = t >> 3, j = t & 7;
        const int q = (j < 4) ? j : (128 + j);      // pads: quads 0-3, 132-135
        *(float4*)&Vl[r][4 * q] = make_float4(0.f, 0.f, 0.f, 0.f);
    }

    // ---- phase 1: vertical 31-row running sums, cols 2t and 2t+1 ----
    const float2* t2p = (const float2*)tgb;
    auto ld = [&](int k) -> float2 {
        const int yy = r0 - 15 + k;
        return (yy >= 0 && yy < HH) ? t2p[yy * (WW / 2) + t]
                                    : make_float2(0.f, 0.f);
    };
    float2 buf[8], sv[16];                   // 8-deep prefetch ring + leavers
    #pragma unroll
    for (int i = 0; i < 8; ++i) buf[i] = ld(i);
    float a0 = 0.f, a1 = 0.f;
    #pragma unroll
    for (int k = 0; k < 38; ++k) {           // by k=37 ALL 46 loads are issued
        const float2 a = buf[k & 7];
        if (k < 16) sv[k] = a;               // rows that will exit the window
        if (k + 8 < NLOAD) buf[k & 7] = ld(k + 8);
        a0 += a.x; a1 += a.y;
        if (k >= 30) {                       // emit V rows 0..7
            *(float2*)&Vl[k - 30][4 * QP + 2 * t] = make_float2(a0, a1);
            a0 -= sv[k - 30].x; a1 -= sv[k - 30].y;
        }
    }
    BARRIER_LDS();                           // V rows 0..7 visible; tail loads
                                             // stay in flight (no vmcnt drain)

    // ---- phase 2 helper: lane owns quads 2l, 2l+1 of row w+4i ----
    float a_bce = 0.f, a_w = 0.f, a_i = 0.f, a_u = 0.f;
    auto qsum = [](const float4 v) { return (v.x + v.y) + (v.z + v.w); };
    auto do_row = [&](int i) {
        const int row = w + 4 * i;
        const float* Vrow = &Vl[row][0];     // padded: real quad q at q+QP
        float4 P[10];                         // padded quads 2l .. 2l+9
        #pragma unroll
        for (int j = 0; j < 10; ++j)
            P[j] = *(const float4*)(Vrow + 4 * (2 * lane + j));
        const float4* t4 = (const float4*)(tgb + (size_t)(r0 + row) * WW);
        const float4 tA = t4[2 * lane], tB = t4[2 * lane + 1];   // L1/L2-hot
        const float s1 = qsum(P[1]), s2 = qsum(P[2]), s3 = qsum(P[3]),
                    s4 = qsum(P[4]), s5 = qsum(P[5]), s6 = qsum(P[6]),
                    s7 = qsum(P[7]), s8 = qsum(P[8]);
        const float F0 = ((s1 + s2) + (s3 + s4)) + ((s5 + s6) + s7);
        {   // quad 2l: L = V[2l-4], U = V[2l+4]
            const float4 L = P[0], U = P[8];
            const float h0 = F0 + ((L.y + L.z) + L.w);
            const float h1 = F0 + ((L.z + L.w) + U.x);
            const float h2 = F0 + (L.w + (U.x + U.y));
            const float h3 = F0 + ((U.x + U.y) + U.z);
            elemwise4(h0, h1, h2, h3, tA, tP[i][0], a_bce, a_w, a_i, a_u);
        }
        const float F1 = (F0 - s1) + s8;
        {   // quad 2l+1: L = V[2l-3], U = V[2l+5]
            const float4 L = P[1], U = P[9];
            const float h0 = F1 + ((L.y + L.z) + L.w);
            const float h1 = F1 + ((L.z + L.w) + U.x);
            const float h2 = F1 + (L.w + (U.x + U.y));
            const float h3 = F1 + ((U.x + U.y) + U.z);
            elemwise4(h0, h1, h2, h3, tB, tP[i][1], a_bce, a_w, a_i, a_u);
        }
    };

    // ---- chunk A: rows 0..7 (waves' i=0,1) overlap the tail-load drain ----
    do_row(0);
    do_row(1);

    // ---- phase-1 tail: k=38..45, no new loads, emits V rows 8..15 ----
    #pragma unroll
    for (int k = 38; k < NLOAD; ++k) {
        const float2 a = buf[k & 7];
        a0 += a.x; a1 += a.y;
        *(float2*)&Vl[k - 30][4 * QP + 2 * t] = make_float2(a0, a1);
        a0 -= sv[k - 30].x; a1 -= sv[k - 30].y;
    }
    BARRIER_LDS();                           // V rows 8..15 visible

    // ---- chunk B: rows 8..15 ----
    do_row(2);
    do_row(3);

    #pragma unroll
    for (int off = 32; off > 0; off >>= 1) {
        a_bce += __shfl_down(a_bce, off, 64);
        a_w   += __shfl_down(a_w,   off, 64);
        a_i   += __shfl_down(a_i,   off, 64);
        a_u   += __shfl_down(a_u,   off, 64);
    }
    if (lane == 0) comb[w] = make_float4(a_bce, a_w, a_i, a_u);
    __syncthreads();
    if (t == 0) {
        const float4 c0 = comb[0], c1 = comb[1];
        const float4 c2 = comb[2], c3 = comb[3];
        part[bi] = make_float4(c0.x + c1.x + c2.x + c3.x,
                               c0.y + c1.y + c2.y + c3.y,
                               c0.z + c1.z + c2.z + c3.z,
                               c0.w + c1.w + c2.w + c3.w);
    }
}

// ---- deterministic tree over 1024 partials, then the scalar formula ----
__global__ __launch_bounds__(1024)
void finalize3_kernel(const float4* __restrict__ part, float* __restrict__ out)
{
    const int lane = threadIdx.x & 63;
    const int w    = threadIdx.x >> 6;      // 16 waves; each handles 2 images
    __shared__ float4 sums[BB];

    #pragma unroll
    for (int s = 0; s < 2; ++s) {
        const int img = w * 2 + s;
        float4 acc = make_float4(0.f, 0.f, 0.f, 0.f);
        if (lane < NSTR) acc = part[img * NSTR + lane];   // 32 partials/image
        #pragma unroll
        for (int off = 32; off > 0; off >>= 1) {
            acc.x += __shfl_down(acc.x, off, 64);
            acc.y += __shfl_down(acc.y, off, 64);
            acc.z += __shfl_down(acc.z, off, 64);
            acc.w += __shfl_down(acc.w, off, 64);
        }
        if (lane == 0) sums[img] = acc;
    }
    __syncthreads();

    if (w == 0) {
        float bsum = (lane < BB) ? sums[lane].x : 0.f;
        #pragma unroll
        for (int off = 32; off > 0; off >>= 1) bsum += __shfl_down(bsum, off, 64);
        const float bce = __shfl(bsum, 0, 64) * (1.0f / NPIX_F);

        float val = 0.f;
        if (lane < BB) {
            const float wsum  = sums[lane].y;
            const float inter = sums[lane].z;
            const float uni   = sums[lane].w;
            const float w_bce = (wsum * bce + 1e-8f) / (wsum + 1e-8f);
            const float w_iou = 1.0f - (inter + 1.0f + 1e-8f) / (uni - inter + 1.0f + 1e-8f);
            val = w_bce + w_iou;
        }
        #pragma unroll
        for (int off = 32; off > 0; off >>= 1) val += __shfl_down(val, off, 64);
        if (lane == 0) out[0] = val * (1.0f / BB);
    }
}

extern "C" void kernel_launch(void* const* d_in, const int* in_sizes, int n_in,
                              void* d_out, int out_size, void* d_ws, size_t ws_size,
                              hipStream_t stream)
{
    (void)in_sizes; (void)n_in; (void)out_size; (void)ws_size;
    const float* pred = (const float*)d_in[0];   // y_pred
    const float* targ = (const float*)d_in[1];   // y_target
    float* out = (float*)d_out;
    float4* part = (float4*)d_ws;                // 1024 * 16 B = 16 KiB

    hipLaunchKernelGGL(fused_kernel, dim3(NB), dim3(256), 0, stream,
                       pred, targ, part);
    hipLaunchKernelGGL(finalize3_kernel, dim3(1), dim3(1024), 0, stream,
                       part, out);
}

// Round 3
// 102.426 us; speedup vs baseline: 1.1349x; 1.1349x over previous
//
#include <hip/hip_runtime.h>
#include <hip/hip_fp16.h>

#define BB 32
#define HH 512
#define WW 512
#define HW (HH * WW)
#define NPIX_F 8388608.0f          // 32*512*512
#define R1 16                      // output rows per block
#define NSTR (HH / R1)             // 32 stripes per image
#define NB (BB * NSTR)             // 1024 blocks (one full residency round)
#define NLOAD (R1 + 30)            // 46 input rows per stripe
#define QP 4                       // quad halo padding each side
#define NQP (128 + 2 * QP)         // 136 padded quads per row
#define VROWH (NQP * 4)            // 544 halves per V row (1088 B)

// lgkmcnt-only barrier: LDS writes visible to the block WITHOUT draining
// vmcnt — in-flight global loads survive it (their vmcnt waits happen at use).
#define BARRIER_LDS() asm volatile("s_waitcnt lgkmcnt(0)\n\ts_barrier" ::: "memory")

__device__ __forceinline__ void elemwise4(const float h0, const float h1,
                                          const float h2, const float h3,
                                          const float4 t, const float4 p,
                                          float& a_bce, float& a_w,
                                          float& a_i, float& a_u)
{
    const float hv[4] = {h0, h1, h2, h3};
    const float tv[4] = {t.x, t.y, t.z, t.w};
    const float pv[4] = {p.x, p.y, p.z, p.w};
    const float inv961 = (1.0f / 961.0f);
    #pragma unroll
    for (int j = 0; j < 4; ++j) {
        const float ap = hv[j] * inv961;
        const float w  = fmaf(5.0f, fabsf(ap - tv[j]), 1.0f);
        const float pr = pv[j];
        const float ea = __expf(-fabsf(pr));                  // exp(-|pr|)
        const float iv = __builtin_amdgcn_rcpf(1.0f + ea);
        const float pp = (pr >= 0.0f) ? iv : (1.0f - iv);     // sigmoid
        const float sp = fmaxf(pr, 0.0f) + __logf(1.0f + ea); // softplus
        a_bce += sp - pr * tv[j];
        a_w   += w;
        a_i   += pp * tv[j] * w;
        a_u   += (pp + tv[j]) * w;
    }
}

// One block = one (image, 16-row stripe). Round-1 skeleton (monolithic
// phase 1 -> barrier -> phase 2; disjoint register liveness, no spills).
// Phase 1: vertical 31-row running sums -> LDS as fp16 V (validated by the
// round-0 session-best) PLUS fp32 per-quad sums Lq (one shfl_xor per emit).
// Phase 2: F = 7x ds_read_b32 from Lq + 2x ds_read_b64 fp16 edge quads
// (44 B/quad vs 144 B in round 1). Pred preloaded (cold); targ re-read hot.
__global__ __launch_bounds__(256, 4)
void fused_kernel(const float* __restrict__ pred, const float* __restrict__ targ,
                  float4* __restrict__ part)
{
    const int t    = threadIdx.x;          // 0..255
    const int lane = t & 63;
    const int w    = t >> 6;               // wave 0..3
    // XCD-bijective swizzle: each XCD gets 128 consecutive ids = 4 images.
    const int orig = blockIdx.x;
    const int bi   = (orig & 7) * (NB / 8) + (orig >> 3);
    const int stripe = bi & (NSTR - 1);
    const int b      = bi >> 5;
    const int r0 = stripe * R1;

    __shared__ __align__(16) __half Vh[R1][VROWH];   // 17408 B
    __shared__ __align__(16) float  Lq[R1][NQP];     //  8704 B
    __shared__ float4 comb[4];

    const float* tgb = targ + (size_t)b * HW;
    const float* prb = pred + (size_t)b * HW;

    // ---- phase 1 ring: issue the first 8 targ row-loads FIRST ----
    const float2* t2p = (const float2*)tgb;
    auto ld = [&](int k) -> float2 {
        const int yy = r0 - 15 + k;
        return (yy >= 0 && yy < HH) ? t2p[yy * (WW / 2) + t]
                                    : make_float2(0.f, 0.f);
    };
    float2 buf[8], sv[16];
    #pragma unroll
    for (int i = 0; i < 8; ++i) buf[i] = ld(i);

    // ---- then preload pred (drains behind the ring; overlaps phase 1) ----
    float4 tP[4][2];
    #pragma unroll
    for (int i = 0; i < 4; ++i) {
        const float4* p4 = (const float4*)(prb + (size_t)(r0 + w * 4 + i) * WW);
        tP[i][0] = p4[lane];
        tP[i][1] = p4[64 + lane];
    }

    // ---- zero halos: V quads and Lq entries 0..3 / 132..135 per row ----
    if (t < 128) {
        const int r = t >> 3, j = t & 7;
        const int q = (j < 4) ? j : (128 + j);       // padded idx 0-3, 132-135
        *(uint2*)&Vh[r][4 * q] = make_uint2(0u, 0u); // 4 halves = 8 B
        Lq[r][q] = 0.f;
    }

    // ---- phase 1: vertical running sums, cols 2t,2t+1; emit V + Lq ----
    float a0 = 0.f, a1 = 0.f;
    #pragma unroll
    for (int k = 0; k < NLOAD; ++k) {
        const float2 a = buf[k & 7];
        if (k < 16) sv[k] = a;               // rows that will exit the window
        if (k + 8 < NLOAD) buf[k & 7] = ld(k + 8);
        a0 += a.x; a1 += a.y;
        if (k >= 30) {
            const int y = k - 30;
            *(__half2*)&Vh[y][4 * QP + 2 * t] = __floats2half2_rn(a0, a1);
            float s = a0 + a1;               // quad sum: lane pair (2q,2q+1)
            s += __shfl_xor(s, 1, 64);
            if (!(t & 1)) Lq[y][QP + (t >> 1)] = s;
            a0 -= sv[y].x; a1 -= sv[y].y;
        }
    }

    // ---- phase-2 targ loads: issue before the barrier (L1/L2-hot) ----
    float4 tT[4][2];
    #pragma unroll
    for (int i = 0; i < 4; ++i) {
        const float4* t4 = (const float4*)(tgb + (size_t)(r0 + w * 4 + i) * WW);
        tT[i][0] = t4[lane];
        tT[i][1] = t4[64 + lane];
    }
    BARRIER_LDS();                           // LDS visible; loads stay in flight

    // ---- phase 2: F from Lq, edges from fp16 V, elementwise ----
    float a_bce = 0.f, a_w = 0.f, a_i = 0.f, a_u = 0.f;
    #pragma unroll
    for (int i = 0; i < 4; ++i) {
        const int row = w * 4 + i;
        const float*  lq = &Lq[row][QP];
        const __half* vr = &Vh[row][0];
        #pragma unroll
        for (int hf = 0; hf < 2; ++hf) {
            const int q = hf * 64 + lane;    // owned quad
            const float F = ((lq[q - 3] + lq[q - 2]) + (lq[q - 1] + lq[q]))
                          + ((lq[q + 1] + lq[q + 2]) + lq[q + 3]);
            const uint2 Lu = *(const uint2*)(vr + 4 * (QP + q - 4));
            const uint2 Uu = *(const uint2*)(vr + 4 * (QP + q + 4));
            const float2 L01 = __half22float2(__builtin_bit_cast(__half2, Lu.x));
            const float2 L23 = __half22float2(__builtin_bit_cast(__half2, Lu.y));
            const float2 U01 = __half22float2(__builtin_bit_cast(__half2, Uu.x));
            const float2 U23 = __half22float2(__builtin_bit_cast(__half2, Uu.y));
            // L quad = cols 4q-16..4q-13; U quad = cols 4q+16..4q+19
            const float h0 = F + ((L01.y + L23.x) + L23.y);  // +cols 4q-15..-13
            const float h1 = F + ((L23.x + L23.y) + U01.x);
            const float h2 = F + ((L23.y + U01.x) + U01.y);
            const float h3 = F + ((U01.x + U01.y) + U23.x);
            elemwise4(h0, h1, h2, h3, tT[i][hf], tP[i][hf],
                      a_bce, a_w, a_i, a_u);
        }
    }

    #pragma unroll
    for (int off = 32; off > 0; off >>= 1) {
        a_bce += __shfl_down(a_bce, off, 64);
        a_w   += __shfl_down(a_w,   off, 64);
        a_i   += __shfl_down(a_i,   off, 64);
        a_u   += __shfl_down(a_u,   off, 64);
    }
    if (lane == 0) comb[w] = make_float4(a_bce, a_w, a_i, a_u);
    __syncthreads();
    if (t == 0) {
        const float4 c0 = comb[0], c1 = comb[1];
        const float4 c2 = comb[2], c3 = comb[3];
        part[bi] = make_float4(c0.x + c1.x + c2.x + c3.x,
                               c0.y + c1.y + c2.y + c3.y,
                               c0.z + c1.z + c2.z + c3.z,
                               c0.w + c1.w + c2.w + c3.w);
    }
}

// ---- deterministic tree over 1024 partials, then the scalar formula ----
__global__ __launch_bounds__(1024)
void finalize3_kernel(const float4* __restrict__ part, float* __restrict__ out)
{
    const int lane = threadIdx.x & 63;
    const int w    = threadIdx.x >> 6;      // 16 waves; each handles 2 images
    __shared__ float4 sums[BB];

    #pragma unroll
    for (int s = 0; s < 2; ++s) {
        const int img = w * 2 + s;
        float4 acc = make_float4(0.f, 0.f, 0.f, 0.f);
        if (lane < NSTR) acc = part[img * NSTR + lane];   // 32 partials/image
        #pragma unroll
        for (int off = 32; off > 0; off >>= 1) {
            acc.x += __shfl_down(acc.x, off, 64);
            acc.y += __shfl_down(acc.y, off, 64);
            acc.z += __shfl_down(acc.z, off, 64);
            acc.w += __shfl_down(acc.w, off, 64);
        }
        if (lane == 0) sums[img] = acc;
    }
    __syncthreads();

    if (w == 0) {
        float bsum = (lane < BB) ? sums[lane].x : 0.f;
        #pragma unroll
        for (int off = 32; off > 0; off >>= 1) bsum += __shfl_down(bsum, off, 64);
        const float bce = __shfl(bsum, 0, 64) * (1.0f / NPIX_F);

        float val = 0.f;
        if (lane < BB) {
            const float wsum  = sums[lane].y;
            const float inter = sums[lane].z;
            const float uni   = sums[lane].w;
            const float w_bce = (wsum * bce + 1e-8f) / (wsum + 1e-8f);
            const float w_iou = 1.0f - (inter + 1.0f + 1e-8f) / (uni - inter + 1.0f + 1e-8f);
            val = w_bce + w_iou;
        }
        #pragma unroll
        for (int off = 32; off > 0; off >>= 1) val += __shfl_down(val, off, 64);
        if (lane == 0) out[0] = val * (1.0f / BB);
    }
}

extern "C" void kernel_launch(void* const* d_in, const int* in_sizes, int n_in,
                              void* d_out, int out_size, void* d_ws, size_t ws_size,
                              hipStream_t stream)
{
    (void)in_sizes; (void)n_in; (void)out_size; (void)ws_size;
    const float* pred = (const float*)d_in[0];   // y_pred
    const float* targ = (const float*)d_in[1];   // y_target
    float* out = (float*)d_out;
    float4* part = (float4*)d_ws;                // 1024 * 16 B = 16 KiB

    hipLaunchKernelGGL(fused_kernel, dim3(NB), dim3(256), 0, stream,
                       pred, targ, part);
    hipLaunchKernelGGL(finalize3_kernel, dim3(1), dim3(1024), 0, stream,
                       part, out);
}